// Round 1
// 788.549 us; speedup vs baseline: 1.1833x; 1.1833x over previous
//
#include <hip/hip_runtime.h>

// EquivariantMLPBlock on MI355X (gfx950), bf16 MFMA implementation.
// Structure: prep (weight transpose+bf16 cast into d_ws) -> S-GEMM (writes
// scalars to out[:, :512] and ALL 384 sigmoid gates CONTIGUOUSLY to
// out[:, 512:896] -- full-line writes, no read-modify-write) -> T-kernel
// (reads gates at out[:, 768+o], writes out[:, 1280:1920]) -> V-kernel
// (pre-loads gates at out[:, 512+o] into registers, vmcnt(0)+barrier,
// then overwrites out[:, 512:1280]).

typedef unsigned short u16;
typedef short bf16x8 __attribute__((ext_vector_type(8)));   // 8 bf16 in 4 VGPRs
typedef float f32x4 __attribute__((ext_vector_type(4)));

#define ROWLEN 1920   // 512 + 768 + 640

__device__ __forceinline__ u16 f2bf(float f) {
  // round-to-nearest-even bf16 (inputs are finite; no NaN handling needed)
  unsigned int u = __float_as_uint(f);
  u += 0x7fffu + ((u >> 16) & 1u);
  return (u16)(u >> 16);
}

__device__ __forceinline__ float sigmoid_f(float x) {
  return 1.0f / (1.0f + __expf(-x));
}

// ---------------------------------------------------------------------------
// prep: WT0[n][k] = bf16(W0[k][n]) (896x512), WT1[o][i] = bf16(W1[i][o])
// (256x256), WT2[o][i] = bf16(W2[i][o]) (128x128). ~1.06 MB in d_ws.
// ---------------------------------------------------------------------------
__global__ __launch_bounds__(256) void prep_kernel(
    const float* __restrict__ W0, const float* __restrict__ W1,
    const float* __restrict__ W2, u16* __restrict__ WT0,
    u16* __restrict__ WT1, u16* __restrict__ WT2) {
  int idx = blockIdx.x * 256 + threadIdx.x;
  if (idx < 896 * 512) {
    int n = idx >> 9, k = idx & 511;
    WT0[idx] = f2bf(W0[k * 896 + n]);
    return;
  }
  int j = idx - 896 * 512;
  if (j >= 0 && j < 256 * 256) {
    int o = j >> 8, i = j & 255;
    WT1[j] = f2bf(W1[i * 256 + o]);
    return;
  }
  int j2 = idx - (896 * 512 + 256 * 256);
  if (j2 >= 0 && j2 < 128 * 128) {
    int o = j2 >> 7, i = j2 & 127;
    WT2[j2] = f2bf(W2[i * 128 + o]);
  }
}

// ---------------------------------------------------------------------------
// S-kernel: out_s = x[:, :512] @ W0 / sqrt(512).
// Tile: BM=128 (grid.x), BN=128 (grid.y=7), BK=64, 4 waves each 64x64.
// cols <512: leaky_relu -> out[:, col]
// cols 512..895: sigmoid gate -> out[:, col]  (CONTIGUOUS stash; full lines)
// ---------------------------------------------------------------------------
__global__ __launch_bounds__(256) void s_kernel(
    const float* __restrict__ x, const u16* __restrict__ WT0,
    float* __restrict__ out, int N) {
  const int r0 = blockIdx.x * 128;
  const int n0 = blockIdx.y * 128;
  __shared__ __align__(16) u16 As[128 * 72];  // [row][k], stride 72 (pad: 2-way only)
  __shared__ __align__(16) u16 Bs[128 * 72];  // [n][k]

  const int tid = threadIdx.x;
  const int lane = tid & 63, wid = tid >> 6;
  const int wm = wid & 1, wn = wid >> 1;       // wave 2x2 grid over 128x128
  const int lm = lane & 15, lq = lane >> 4;

  f32x4 acc[4][4];
  const f32x4 zero4 = {0.f, 0.f, 0.f, 0.f};
#pragma unroll
  for (int i = 0; i < 4; ++i)
#pragma unroll
    for (int j = 0; j < 4; ++j) acc[i][j] = zero4;

  const int ac = tid & 15;       // A: float4 col group (16 x 4 = 64 floats)
  const int ar = tid >> 4;       // A: row base (16 rows/pass, 8 passes)
  const int bg = tid & 15;       // B: 4-bf16 group
  const int bn = tid >> 4;

  for (int k0 = 0; k0 < 512; k0 += 64) {
    // ---- stage A (128x64 fp32 -> bf16 LDS) ----
    float4 va[8];
#pragma unroll
    for (int p = 0; p < 8; ++p) {
      int rr = ar + p * 16;
      int rg = r0 + rr; if (rg >= N) rg = N - 1;
      va[p] = *(const float4*)(x + (size_t)rg * ROWLEN + k0 + ac * 4);
    }
    // ---- stage B (128n x 64k bf16) ----
    ushort4 vb[8];
#pragma unroll
    for (int p = 0; p < 8; ++p) {
      int nn = bn + p * 16;
      vb[p] = *(const ushort4*)(WT0 + (size_t)(n0 + nn) * 512 + k0 + bg * 4);
    }
#pragma unroll
    for (int p = 0; p < 8; ++p) {
      int rr = ar + p * 16;
      ushort4 h;
      h.x = f2bf(va[p].x); h.y = f2bf(va[p].y);
      h.z = f2bf(va[p].z); h.w = f2bf(va[p].w);
      *(ushort4*)&As[rr * 72 + ac * 4] = h;
    }
#pragma unroll
    for (int p = 0; p < 8; ++p) {
      int nn = bn + p * 16;
      *(ushort4*)&Bs[nn * 72 + bg * 4] = vb[p];
    }
    __syncthreads();

    // ---- compute: 2 k-steps of 32 ----
#pragma unroll
    for (int kk = 0; kk < 64; kk += 32) {
      bf16x8 af[4], bfr[4];
#pragma unroll
      for (int mt = 0; mt < 4; ++mt)
        af[mt] = *(const bf16x8*)&As[(wm * 64 + mt * 16 + lm) * 72 + kk + lq * 8];
#pragma unroll
      for (int nt = 0; nt < 4; ++nt)
        bfr[nt] = *(const bf16x8*)&Bs[(wn * 64 + nt * 16 + lm) * 72 + kk + lq * 8];
#pragma unroll
      for (int mt = 0; mt < 4; ++mt)
#pragma unroll
        for (int nt = 0; nt < 4; ++nt)
          acc[mt][nt] = __builtin_amdgcn_mfma_f32_16x16x32_bf16(
              af[mt], bfr[nt], acc[mt][nt], 0, 0, 0);
    }
    __syncthreads();
  }

  // ---- epilogue: contiguous writes only (no partial-line RMW) ----
  const float scale = 0.04419417382415922f;  // 1/sqrt(512)
#pragma unroll
  for (int mt = 0; mt < 4; ++mt) {
#pragma unroll
    for (int reg = 0; reg < 4; ++reg) {
      int row = r0 + wm * 64 + mt * 16 + lq * 4 + reg;
      if (row >= N) continue;
      float* orow = out + (size_t)row * ROWLEN;
#pragma unroll
      for (int nt = 0; nt < 4; ++nt) {
        int col = n0 + wn * 64 + nt * 16 + lm;
        float v = acc[mt][nt][reg] * scale;
        // col<512 is wave-uniform per nt (boundaries are multiples of 16)
        float r = (col < 512) ? (v > 0.f ? v : 0.01f * v)   // leaky_relu
                              : sigmoid_f(v);               // gate stash
        orow[col] = r;
      }
    }
  }
}

// ---------------------------------------------------------------------------
// V-kernel: v_out[n,o,m] = sum_i x[n,512+3i+m]*W1[i,o] / 16 * gate.
// BM=32 rows/block, all 256 output cols, K chunks of 64 (coalesced read of
// 192 cols de-interleaved into 3 LDS planes). 4 waves each take 64 cols.
// Gates are read from out[row, 512+o] BEFORE overwriting out[row, 512:1280]:
// preload to registers, drain vmcnt, barrier, then store.
// ---------------------------------------------------------------------------
__global__ __launch_bounds__(256) void v_kernel(
    const float* __restrict__ x, const u16* __restrict__ WT1,
    float* __restrict__ out, int N) {
  const int r0 = blockIdx.x * 32;
  __shared__ __align__(16) u16 Av[3 * 32 * 72];  // plane m at m*2304
  __shared__ __align__(16) u16 Bs[256 * 72];

  const int tid = threadIdx.x;
  const int lane = tid & 63, w = tid >> 6;
  const int lm = lane & 15, lq = lane >> 4;

  f32x4 acc[3][2][4];
  const f32x4 zero4 = {0.f, 0.f, 0.f, 0.f};
#pragma unroll
  for (int m = 0; m < 3; ++m)
#pragma unroll
    for (int i = 0; i < 2; ++i)
#pragma unroll
      for (int j = 0; j < 4; ++j) acc[m][i][j] = zero4;

  const int arr = tid >> 3;   // 0..31 row
  const int ag = tid & 7;     // col subgroup
  const int bg = tid & 15, bn = tid >> 4;

  for (int k0 = 0; k0 < 256; k0 += 64) {
    // stage A: 32 rows x 192 cols, scatter to 3 planes [row][i]
    {
      int rg = r0 + arr; if (rg >= N) rg = N - 1;
      const float* src = x + (size_t)rg * ROWLEN + 512 + 3 * k0;
#pragma unroll
      for (int it = 0; it < 6; ++it) {
        int c4 = ag + it * 8;                 // 0..47
        float4 v = *(const float4*)(src + c4 * 4);
        float tmp[4] = {v.x, v.y, v.z, v.w};
#pragma unroll
        for (int jj = 0; jj < 4; ++jj) {
          int j = c4 * 4 + jj;                // 0..191
          int i = j / 3, m = j % 3;
          Av[m * 2304 + arr * 72 + i] = f2bf(tmp[jj]);
        }
      }
    }
    // stage B: 256n x 64k
#pragma unroll
    for (int p = 0; p < 16; ++p) {
      int nn = bn + p * 16;
      *(ushort4*)&Bs[nn * 72 + bg * 4] =
          *(const ushort4*)(WT1 + (size_t)nn * 256 + k0 + bg * 4);
    }
    __syncthreads();

#pragma unroll
    for (int kk = 0; kk < 64; kk += 32) {
      bf16x8 bfr[4];
#pragma unroll
      for (int nt = 0; nt < 4; ++nt)
        bfr[nt] = *(const bf16x8*)&Bs[(w * 64 + nt * 16 + lm) * 72 + kk + lq * 8];
#pragma unroll
      for (int m = 0; m < 3; ++m) {
        bf16x8 af[2];
#pragma unroll
        for (int mt = 0; mt < 2; ++mt)
          af[mt] = *(const bf16x8*)&Av[m * 2304 + (mt * 16 + lm) * 72 + kk + lq * 8];
#pragma unroll
        for (int mt = 0; mt < 2; ++mt)
#pragma unroll
          for (int nt = 0; nt < 4; ++nt)
            acc[m][mt][nt] = __builtin_amdgcn_mfma_f32_16x16x32_bf16(
                af[mt], bfr[nt], acc[m][mt][nt], 0, 0, 0);
      }
    }
    __syncthreads();
  }

  // ---- epilogue: preload gates (dense at out[row, 512+o]), then overwrite ----
  float g[2][4][4];   // [mt][reg][nt]
#pragma unroll
  for (int mt = 0; mt < 2; ++mt) {
#pragma unroll
    for (int reg = 0; reg < 4; ++reg) {
      int row = r0 + mt * 16 + lq * 4 + reg;
      int rc = row < N ? row : (N - 1);   // clamp (value unused for OOB rows)
#pragma unroll
      for (int nt = 0; nt < 4; ++nt) {
        int o = w * 64 + nt * 16 + lm;
        g[mt][reg][nt] = out[(size_t)rc * ROWLEN + 512 + o];
      }
    }
  }
  // all gate loads must land before ANY thread in the block overwrites them
  asm volatile("s_waitcnt vmcnt(0)" ::: "memory");
  __syncthreads();

  const float scale = 0.0625f;  // 1/sqrt(256)
#pragma unroll
  for (int mt = 0; mt < 2; ++mt) {
#pragma unroll
    for (int reg = 0; reg < 4; ++reg) {
      int row = r0 + mt * 16 + lq * 4 + reg;
      if (row >= N) continue;
#pragma unroll
      for (int nt = 0; nt < 4; ++nt) {
        int o = w * 64 + nt * 16 + lm;
        float* p = out + (size_t)row * ROWLEN + 512 + 3 * o;
        float gg = g[mt][reg][nt];
        p[0] = acc[0][mt][nt][reg] * scale * gg;
        p[1] = acc[1][mt][nt][reg] * scale * gg;
        p[2] = acc[2][mt][nt][reg] * scale * gg;
      }
    }
  }
}

// ---------------------------------------------------------------------------
// T-kernel: t_out[n,o,m] = sum_i x[n,1280+5i+m]*W2[i,o] / sqrt(128) * gate.
// BM=32, all 128 cols, K chunks of 64 (coalesced 320-col read -> 5 planes).
// 4 waves each take 32 cols. Gates read densely from out[row, 768+o]
// (disjoint from T's write region -- no race).
// ---------------------------------------------------------------------------
__global__ __launch_bounds__(256) void t_kernel(
    const float* __restrict__ x, const u16* __restrict__ WT2,
    float* __restrict__ out, int N) {
  const int r0 = blockIdx.x * 32;
  __shared__ __align__(16) u16 Av[5 * 32 * 72];  // plane m at m*2304
  __shared__ __align__(16) u16 Bs[128 * 72];

  const int tid = threadIdx.x;
  const int lane = tid & 63, w = tid >> 6;
  const int lm = lane & 15, lq = lane >> 4;

  f32x4 acc[5][2][2];
  const f32x4 zero4 = {0.f, 0.f, 0.f, 0.f};
#pragma unroll
  for (int m = 0; m < 5; ++m)
#pragma unroll
    for (int i = 0; i < 2; ++i)
#pragma unroll
      for (int j = 0; j < 2; ++j) acc[m][i][j] = zero4;

  const int arr = tid >> 3;
  const int ag = tid & 7;
  const int bg = tid & 15, bn = tid >> 4;

  for (int k0 = 0; k0 < 128; k0 += 64) {
    // stage A: 32 rows x 320 cols -> 5 planes
    {
      int rg = r0 + arr; if (rg >= N) rg = N - 1;
      const float* src = x + (size_t)rg * ROWLEN + 1280 + 5 * k0;
#pragma unroll
      for (int it = 0; it < 10; ++it) {
        int c4 = ag + it * 8;                 // 0..79
        float4 v = *(const float4*)(src + c4 * 4);
        float tmp[4] = {v.x, v.y, v.z, v.w};
#pragma unroll
        for (int jj = 0; jj < 4; ++jj) {
          int j = c4 * 4 + jj;                // 0..319
          int i = j / 5, m = j % 5;
          Av[m * 2304 + arr * 72 + i] = f2bf(tmp[jj]);
        }
      }
    }
    // stage B: 128n x 64k
#pragma unroll
    for (int p = 0; p < 8; ++p) {
      int nn = bn + p * 16;
      *(ushort4*)&Bs[nn * 72 + bg * 4] =
          *(const ushort4*)(WT2 + (size_t)nn * 128 + k0 + bg * 4);
    }
    __syncthreads();

#pragma unroll
    for (int kk = 0; kk < 64; kk += 32) {
      bf16x8 bfr[2];
#pragma unroll
      for (int nt = 0; nt < 2; ++nt)
        bfr[nt] = *(const bf16x8*)&Bs[(w * 32 + nt * 16 + lm) * 72 + kk + lq * 8];
#pragma unroll
      for (int m = 0; m < 5; ++m) {
        bf16x8 af[2];
#pragma unroll
        for (int mt = 0; mt < 2; ++mt)
          af[mt] = *(const bf16x8*)&Av[m * 2304 + (mt * 16 + lm) * 72 + kk + lq * 8];
#pragma unroll
        for (int mt = 0; mt < 2; ++mt)
#pragma unroll
          for (int nt = 0; nt < 2; ++nt)
            acc[m][mt][nt] = __builtin_amdgcn_mfma_f32_16x16x32_bf16(
                af[mt], bfr[nt], acc[m][mt][nt], 0, 0, 0);
      }
    }
    __syncthreads();
  }

  const float scale = 0.08838834764831845f;  // 1/sqrt(128)
#pragma unroll
  for (int mt = 0; mt < 2; ++mt) {
#pragma unroll
    for (int reg = 0; reg < 4; ++reg) {
      int row = r0 + mt * 16 + lq * 4 + reg;
      if (row >= N) continue;
#pragma unroll
      for (int nt = 0; nt < 2; ++nt) {
        int o = w * 32 + nt * 16 + lm;
        float g = out[(size_t)row * ROWLEN + 768 + o];  // dense gate stash
        float* p = out + (size_t)row * ROWLEN + 1280 + 5 * o;
#pragma unroll
        for (int m = 0; m < 5; ++m)
          p[m] = acc[m][mt][nt][reg] * scale * g;
      }
    }
  }
}

// ---------------------------------------------------------------------------
extern "C" void kernel_launch(void* const* d_in, const int* in_sizes, int n_in,
                              void* d_out, int out_size, void* d_ws, size_t ws_size,
                              hipStream_t stream) {
  const float* x  = (const float*)d_in[0];
  const float* W0 = (const float*)d_in[1];
  const float* W1 = (const float*)d_in[2];
  const float* W2 = (const float*)d_in[3];
  float* out = (float*)d_out;
  const int N = in_sizes[0] / ROWLEN;  // 50000

  u16* WT0 = (u16*)d_ws;                 // 896*512
  u16* WT1 = WT0 + 896 * 512;            // 256*256
  u16* WT2 = WT1 + 256 * 256;            // 128*128

  prep_kernel<<<(896 * 512 + 256 * 256 + 128 * 128 + 255) / 256, 256, 0, stream>>>(
      W0, W1, W2, WT0, WT1, WT2);

  dim3 sgrid((N + 127) / 128, 7);
  s_kernel<<<sgrid, 256, 0, stream>>>(x, WT0, out, N);

  const int rb32 = (N + 31) / 32;
  // T first: reads gates at out[:, 768:896] which it does not overwrite.
  t_kernel<<<rb32, 256, 0, stream>>>(x, WT2, out, N);
  // V last: preloads gates at out[:, 512:768] before overwriting out[:, 512:1280].
  v_kernel<<<rb32, 256, 0, stream>>>(x, WT1, out, N);
}